// Round 1
// baseline (83.075 us; speedup 1.0000x reference)
//
#include <hip/hip_runtime.h>
#include <hip/hip_bf16.h>

// LocalPPM: B=4, C=256, H=W=56, R=2 (5x5 -> K2=25), TOPK=10, TAU=0.1, EPS=1e-8
// out = x + gamma * sum_k softmax_top10(cos_sim(center, neighbor_k)/TAU) * neighbor_k
//
// ws layout: dot[B][25][3136] floats (1,254,400 B) then wts[B][25][3136] floats.

#define PX 3136   // 56*56
#define CS 3136   // channel plane stride (H*W)

__global__ void k_dot(const float* __restrict__ x, float* __restrict__ dot) {
    const int p  = blockIdx.x * 64 + threadIdx.x;   // 0..3135
    const int dy = blockIdx.y;                      // 0..4
    const int b  = blockIdx.z;                      // 0..3
    const int h  = p / 56;
    const int w  = p - h * 56;
    const int r  = h + dy - 2;

    float a0 = 0.f, a1 = 0.f, a2 = 0.f, a3 = 0.f, a4 = 0.f;

    if (r >= 0 && r < 56) {
        const bool cv0 = (w >= 2), cv1 = (w >= 1), cv3 = (w <= 54), cv4 = (w <= 53);
        const float* xb = x + (size_t)b * 256 * CS;
        const float* cp = xb + p;            // center value, +c*CS per channel
        const float* q0 = xb + r * 56 + w;   // neighbor row, dx offsets -2..+2
        #pragma unroll 4
        for (int c = 0; c < 256; ++c) {
            const float ctr = cp[c * CS];
            const float* q = q0 + c * CS;
            const float n0 = cv0 ? q[-2] : 0.f;
            const float n1 = cv1 ? q[-1] : 0.f;
            const float n2 = q[0];
            const float n3 = cv3 ? q[1] : 0.f;
            const float n4 = cv4 ? q[2] : 0.f;
            a0 = fmaf(ctr, n0, a0);
            a1 = fmaf(ctr, n1, a1);
            a2 = fmaf(ctr, n2, a2);
            a3 = fmaf(ctr, n3, a3);
            a4 = fmaf(ctr, n4, a4);
        }
    }
    float* dp = dot + ((size_t)(b * 25 + dy * 5)) * PX + p;
    dp[0 * PX] = a0;
    dp[1 * PX] = a1;
    dp[2 * PX] = a2;
    dp[3 * PX] = a3;
    dp[4 * PX] = a4;
}

__global__ void k_wts(const float* __restrict__ dot, float* __restrict__ wts) {
    const int p = blockIdx.x * 64 + threadIdx.x;
    const int b = blockIdx.y;
    const int h = p / 56;
    const int w = p - h * 56;
    const float* db = dot + (size_t)b * 25 * PX;

    const float n2c = db[12 * PX + p];
    const float cn  = sqrtf(n2c);

    float s[25];
    #pragma unroll
    for (int k = 0; k < 25; ++k) {
        const int dy = k / 5, dx = k % 5;
        const int rr = h + dy - 2, cc = w + dx - 2;
        const bool v = (rr >= 0) && (rr < 56) && (cc >= 0) && (cc < 56);
        float d = 0.f, n2 = 0.f;
        if (v) {
            d  = db[k * PX + p];
            n2 = db[12 * PX + rr * 56 + cc];
        }
        // sims = dot / max(pn*cn, EPS) / TAU
        s[k] = d / fmaxf(sqrtf(n2) * cn, 1e-8f) * 10.f;
    }

    // global max (the max element always survives top-k)
    float m = s[0];
    #pragma unroll
    for (int k = 1; k < 25; ++k) m = fmaxf(m, s[k]);

    // exact top-10 selection with JAX tie-break (value desc, index asc):
    // rank(k) = #{j: s_j > s_k} + #{j<k: s_j == s_k}; keep if rank < 10.
    unsigned sel = 0u;
    float denom = 0.f;
    #pragma unroll
    for (int k = 0; k < 25; ++k) {
        int rank = 0;
        #pragma unroll
        for (int j = 0; j < 25; ++j) {
            rank += (int)((s[j] > s[k]) || ((s[j] == s[k]) && (j < k)));
        }
        if (rank < 10) {
            sel |= (1u << k);
            denom += __expf(s[k] - m);
        }
    }
    const float inv = 1.f / denom;

    float* wb = wts + (size_t)b * 25 * PX + p;
    #pragma unroll
    for (int k = 0; k < 25; ++k) {
        const float wk = ((sel >> k) & 1u) ? __expf(s[k] - m) * inv : 0.f;
        wb[k * PX] = wk;
    }
}

__global__ void k_out(const float* __restrict__ x, const float* __restrict__ wts,
                      const float* __restrict__ gptr, float* __restrict__ out) {
    const int p  = blockIdx.x * 64 + threadIdx.x;
    const int cg = blockIdx.y;                     // 0..31, 8 channels each
    const int b  = blockIdx.z;
    const int h  = p / 56;
    const int w  = p - h * 56;
    const float g = *gptr;

    float wk[25];
    const float* wb = wts + (size_t)b * 25 * PX + p;
    #pragma unroll
    for (int k = 0; k < 25; ++k) wk[k] = wb[k * PX];

    const float* xb = x   + ((size_t)b * 256 + cg * 8) * CS;
    float*       ob = out + ((size_t)b * 256 + cg * 8) * CS;

    #pragma unroll 2
    for (int ci = 0; ci < 8; ++ci) {
        const float* xp = xb + ci * CS;
        float y = 0.f;
        #pragma unroll
        for (int k = 0; k < 25; ++k) {
            const int dy = k / 5, dx = k % 5;
            const int rr = h + dy - 2, cc = w + dx - 2;
            const bool v = (rr >= 0) && (rr < 56) && (cc >= 0) && (cc < 56);
            const float xv = v ? xp[p + (dy - 2) * 56 + (dx - 2)] : 0.f;
            y = fmaf(wk[k], xv, y);
        }
        ob[ci * CS + p] = xp[p] + g * y;
    }
}

extern "C" void kernel_launch(void* const* d_in, const int* in_sizes, int n_in,
                              void* d_out, int out_size, void* d_ws, size_t ws_size,
                              hipStream_t stream) {
    const float* x     = (const float*)d_in[0];
    const float* gamma = (const float*)d_in[1];
    float* out = (float*)d_out;

    float* dot = (float*)d_ws;                 // [4][25][3136]
    float* wts = dot + 4 * 25 * PX;            // [4][25][3136]

    k_dot<<<dim3(49, 5, 4), 64, 0, stream>>>(x, dot);
    k_wts<<<dim3(49, 4), 64, 0, stream>>>(dot, wts);
    k_out<<<dim3(49, 32, 4), 64, 0, stream>>>(x, wts, gamma, out);
}

// Round 2
// 50.993 us; speedup vs baseline: 1.6291x; 1.6291x over previous
//
#include <hip/hip_runtime.h>
#include <hip/hip_bf16.h>

// LocalPPM: B=4, C=256, H=W=56, R=2 (5x5 -> K2=25), TOPK=10, TAU=0.1, EPS=1e-8
// out = x + gamma * sum_k softmax_top10(cos_sim(center, neighbor_k)/TAU) * neighbor_k
//
// Symmetry: dot(p, +o) == dot(p+o, -o), so only the 13 offsets k=0..12
// (dy=-2,-1 full rows; dy=0, dx<=0) are computed; k_wts mirrors the rest.
//
// ws layout: dot[B][13][3136] floats (652 KB) then wts[B][25][3136] floats.

#define PX 3136   // 56*56
#define CS 3136   // channel plane stride (H*W)

// block: 512 threads = 64 pixels x 8 channel-chunks (32 ch each). grid (49,3,4).
__global__ __launch_bounds__(512) void k_dot(const float* __restrict__ x,
                                             float* __restrict__ dot) {
    const int px  = threadIdx.x & 63;
    const int cc8 = threadIdx.x >> 6;              // 0..7 channel chunk
    const int p   = blockIdx.x * 64 + px;
    const int dyb = blockIdx.y;                    // 0,1,2 -> dy = dyb-2
    const int b   = blockIdx.z;
    const int h   = p / 56;
    const int w   = p - h * 56;
    const int r   = h + dyb - 2;                   // r <= h, only lower bound matters

    float a0 = 0.f, a1 = 0.f, a2 = 0.f, a3 = 0.f, a4 = 0.f;

    if (r >= 0) {
        const bool cv0 = (w >= 2), cv1 = (w >= 1), cv3 = (w <= 54), cv4 = (w <= 53);
        const float* xb = x + (size_t)b * 256 * CS + (size_t)cc8 * 32 * CS;
        const float* cp = xb + p;
        const float* q0 = xb + r * 56 + w;
        #pragma unroll 4
        for (int c = 0; c < 32; ++c) {
            const float ctr = cp[c * CS];
            const float* q = q0 + c * CS;
            const float n0 = cv0 ? q[-2] : 0.f;
            const float n1 = cv1 ? q[-1] : 0.f;
            const float n2 = q[0];
            const float n3 = cv3 ? q[1] : 0.f;
            const float n4 = cv4 ? q[2] : 0.f;
            a0 = fmaf(ctr, n0, a0);
            a1 = fmaf(ctr, n1, a1);
            a2 = fmaf(ctr, n2, a2);
            a3 = fmaf(ctr, n3, a3);
            a4 = fmaf(ctr, n4, a4);
        }
    }

    __shared__ float part[8][5][64];
    part[cc8][0][px] = a0;
    part[cc8][1][px] = a1;
    part[cc8][2][px] = a2;
    part[cc8][3][px] = a3;
    part[cc8][4][px] = a4;
    __syncthreads();

    const int nacc = (dyb == 2) ? 3 : 5;           // dy=0 row: only dx=-2..0
    const int i = threadIdx.x;
    if (i < 5 * 64) {
        const int acc = i >> 6, pp = i & 63;
        if (acc < nacc) {
            float sum = 0.f;
            #pragma unroll
            for (int j = 0; j < 8; ++j) sum += part[j][acc][pp];
            dot[((size_t)(b * 13 + dyb * 5 + acc)) * PX + blockIdx.x * 64 + pp] = sum;
        }
    }
}

__global__ void k_wts(const float* __restrict__ dot, float* __restrict__ wts) {
    const int p = blockIdx.x * 64 + threadIdx.x;
    const int b = blockIdx.y;
    const int h = p / 56;
    const int w = p - h * 56;
    const float* db = dot + (size_t)b * 13 * PX;

    const float cn = sqrtf(db[12 * PX + p]);

    float s[25];
    #pragma unroll
    for (int k = 0; k < 25; ++k) {
        const int dy = k / 5 - 2, dx = k % 5 - 2;
        const int rr = h + dy, cc = w + dx;
        const bool v = (rr >= 0) && (rr < 56) && (cc >= 0) && (cc < 56);
        float d = 0.f, n2 = 0.f;
        if (v) {
            const int q = rr * 56 + cc;
            n2 = db[12 * PX + q];
            d  = (k <= 12) ? db[k * PX + p] : db[(24 - k) * PX + q];
        }
        s[k] = d / fmaxf(sqrtf(n2) * cn, 1e-8f) * 10.f;
    }

    float m = s[0];
    #pragma unroll
    for (int k = 1; k < 25; ++k) m = fmaxf(m, s[k]);

    // exact top-10 with JAX tie-break (value desc, index asc)
    unsigned sel = 0u;
    float denom = 0.f;
    #pragma unroll
    for (int k = 0; k < 25; ++k) {
        int rank = 0;
        #pragma unroll
        for (int j = 0; j < 25; ++j) {
            rank += (int)((s[j] > s[k]) || ((s[j] == s[k]) && (j < k)));
        }
        if (rank < 10) {
            sel |= (1u << k);
            denom += __expf(s[k] - m);
        }
    }
    const float inv = 1.f / denom;

    float* wb = wts + (size_t)b * 25 * PX + p;
    #pragma unroll
    for (int k = 0; k < 25; ++k) {
        const float wk = ((sel >> k) & 1u) ? __expf(s[k] - m) * inv : 0.f;
        wb[k * PX] = wk;
    }
}

__global__ void k_out(const float* __restrict__ x, const float* __restrict__ wts,
                      const float* __restrict__ gptr, float* __restrict__ out) {
    const int p  = blockIdx.x * 64 + threadIdx.x;
    const int cg = blockIdx.y;                     // 0..31, 8 channels each
    const int b  = blockIdx.z;
    const int h  = p / 56;
    const int w  = p - h * 56;
    const float g = *gptr;

    float wk[25];
    const float* wb = wts + (size_t)b * 25 * PX + p;
    #pragma unroll
    for (int k = 0; k < 25; ++k) wk[k] = wb[k * PX];

    const float* xb = x   + ((size_t)b * 256 + cg * 8) * CS;
    float*       ob = out + ((size_t)b * 256 + cg * 8) * CS;

    #pragma unroll 2
    for (int ci = 0; ci < 8; ++ci) {
        const float* xp = xb + ci * CS;
        float y = 0.f;
        #pragma unroll
        for (int k = 0; k < 25; ++k) {
            const int dy = k / 5 - 2, dx = k % 5 - 2;
            const int rr = h + dy, cc = w + dx;
            const bool v = (rr >= 0) && (rr < 56) && (cc >= 0) && (cc < 56);
            const float xv = v ? xp[p + dy * 56 + dx] : 0.f;
            y = fmaf(wk[k], xv, y);
        }
        ob[ci * CS + p] = xp[p] + g * y;
    }
}

extern "C" void kernel_launch(void* const* d_in, const int* in_sizes, int n_in,
                              void* d_out, int out_size, void* d_ws, size_t ws_size,
                              hipStream_t stream) {
    const float* x     = (const float*)d_in[0];
    const float* gamma = (const float*)d_in[1];
    float* out = (float*)d_out;

    float* dot = (float*)d_ws;                 // [4][13][3136]
    float* wts = dot + 4 * 13 * PX;            // [4][25][3136]

    k_dot<<<dim3(49, 3, 4), 512, 0, stream>>>(x, dot);
    k_wts<<<dim3(49, 4), 64, 0, stream>>>(dot, wts);
    k_out<<<dim3(49, 32, 4), 64, 0, stream>>>(x, wts, gamma, out);
}